// Round 7
// baseline (8989.763 us; speedup 1.0000x reference)
//
#include <hip/hip_runtime.h>

// SparseConv3d rulebook scatter-GEMM, MI355X (gfx950)
// R7: bins = (k, 256-row out-tile, input-slice); persistent gather kernel
// (1024 blocks, all co-resident) sweeps input slices in phase so the 32 MB
// bf16 x-slice stays L3-resident. Out merged per slice with NT load/store.

#define K3    27
#define RULES 1000000
#define CIN   32
#define COUT  32
#define NIN   2000000
#define NOUT  2000000
#define TR    256
#define NT    ((NOUT + TR - 1) / TR)   // 7813 tiles
#define NSLICE 4
#define SLICE_SHIFT 19                 // 512K input rows per slice
#define NBINS2 (K3 * NT * NSLICE)      // 843,804 bins
#define CAPB2 96                       // avg 32 rules/bin
#define OVFCAP 4096
#define NBLK  1024                     // 4 blocks/CU * 256 CU -> one generation
#define TPB   8                        // tiles per block (strided)

typedef float f32x4 __attribute__((ext_vector_type(4)));
typedef short bf16x8 __attribute__((ext_vector_type(8)));
typedef unsigned short us8 __attribute__((ext_vector_type(8)));

union BF8 {
  bf16x8 v;
  unsigned short u[8];
};

static __device__ inline unsigned short f2bf(float f) {
  unsigned u = __builtin_bit_cast(unsigned, f);
  u += 0x7fffu + ((u >> 16) & 1u);   // RNE
  return (unsigned short)(u >> 16);
}

// ---------------- x -> bf16 conversion (NT both ways) ----------------
__global__ __launch_bounds__(256) void xcvt_kernel(
    const float* __restrict__ x, unsigned short* __restrict__ xbf) {
  const size_t n8 = (size_t)NIN * CIN / 8;
  const size_t stride = (size_t)gridDim.x * 256;
  for (size_t i = (size_t)blockIdx.x * 256 + threadIdx.x; i < n8; i += stride) {
    const f32x4* p = reinterpret_cast<const f32x4*>(x + i * 8);
    const f32x4 a = __builtin_nontemporal_load(p);
    const f32x4 b = __builtin_nontemporal_load(p + 1);
    us8 o;
    o[0] = f2bf(a[0]); o[1] = f2bf(a[1]); o[2] = f2bf(a[2]); o[3] = f2bf(a[3]);
    o[4] = f2bf(b[0]); o[5] = f2bf(b[1]); o[6] = f2bf(b[2]); o[7] = f2bf(b[3]);
    __builtin_nontemporal_store(o, reinterpret_cast<us8*>(xbf + i * 8));
  }
}

// ---------------- capacity-binned single-pass place ----------------
__global__ __launch_bounds__(256) void place_cap_kernel(
    const int* __restrict__ in_inds, const int* __restrict__ out_inds,
    int* __restrict__ cnt, unsigned* __restrict__ entries,
    int* __restrict__ ovfc, unsigned* __restrict__ ovf) {
  const int k = blockIdx.y;
  const int e = blockIdx.x * 256 + threadIdx.x;
  if (e >= RULES) return;
  const size_t idx = (size_t)k * RULES + e;
  const int oi = __builtin_nontemporal_load(out_inds + idx);
  const int ii = __builtin_nontemporal_load(in_inds + idx);
  const int bin = (k * NT + (oi >> 8)) * NSLICE + (ii >> SLICE_SHIFT);
  const int pos = atomicAdd(&cnt[bin], 1);
  if (pos < CAPB2) {
    __builtin_nontemporal_store(((unsigned)ii << 8) | (unsigned)(oi & 255),
                                entries + (size_t)bin * CAPB2 + pos);
  } else {
    const int op = atomicAdd(ovfc, 1);
    if (op < OVFCAP) {
      ovf[op * 2] = (unsigned)ii;
      ovf[op * 2 + 1] = (unsigned)oi | ((unsigned)k << 21);
    }
  }
}

// ---------------- fixup for (expected-zero) bin overflow ----------------
// Must run AFTER gather (adds on top of finalized out).
__global__ __launch_bounds__(256) void fixup_kernel(
    const float* __restrict__ x, const float* __restrict__ weights,
    const int* __restrict__ ovfc, const unsigned* __restrict__ ovf,
    float* __restrict__ out) {
  const int m = min(*ovfc, OVFCAP);
  const int total = m * 32;
  for (int idx = blockIdx.x * 256 + threadIdx.x; idx < total;
       idx += gridDim.x * 256) {
    const int rr = idx >> 5, c = idx & 31;
    const unsigned ii = ovf[rr * 2];
    const unsigned w1 = ovf[rr * 2 + 1];
    const unsigned oi = w1 & 0x1FFFFFu;
    const int k = (int)(w1 >> 21);
    const float* xr = x + (size_t)ii * CIN;
    const float* wk = weights + (size_t)k * CIN * COUT;
    float acc = 0.f;
#pragma unroll
    for (int i = 0; i < CIN; ++i) acc += xr[i] * wk[i * COUT + c];
    atomicAdd(&out[(size_t)oi * COUT + c], acc);
  }
}

// ---------------- sliced persistent MFMA gather-compute ----------------
// 1024 blocks x 256 threads (4 waves), 4 blocks/CU -> ALL blocks resident.
// for slice { for my tiles (strided) { zero LDS acc; 4 waves cover 27 k-bins;
// MFMA per 32-rule group; LDS atomic scatter; NT-merge into out } }.
// Slice-major loop keeps the 32MB bf16 x-slice L3-resident device-wide.
__global__ __launch_bounds__(256, 4) void gather_sliced_kernel(
    const unsigned short* __restrict__ xbf, const float* __restrict__ weights,
    const float* __restrict__ bias, const int* __restrict__ cnt,
    const unsigned* __restrict__ entries, float* __restrict__ out) {
  __shared__ float sacc[257 * 33];
  const int tid = threadIdx.x;
  const int wave = tid >> 6;
  const int lane = tid & 63;
  const int lm = lane & 15;   // rule-in-group / cout col
  const int lk = lane >> 4;   // K-chunk selector
  const f32x4* __restrict__ b4 = reinterpret_cast<const f32x4*>(bias);

  for (int sl = 0; sl < NSLICE; ++sl) {
    for (int ti = 0; ti < TPB; ++ti) {
      const int t = ti * NBLK + blockIdx.x;   // strided tile ownership
      if (t >= NT) continue;

      __syncthreads();
      for (int i = tid; i < 257 * 33; i += 256) sacc[i] = 0.f;
      __syncthreads();

      for (int kk = wave; kk < K3; kk += 4) {
        const int bin = (kk * NT + t) * NSLICE + sl;
        int n = __builtin_amdgcn_readfirstlane(cnt[bin]);
        n = min(n, CAPB2);
        if (n == 0) continue;
        const size_t s = (size_t)bin * CAPB2;

        // B fragments for W[kk] (L2-hot)
        const float* __restrict__ wk = weights + (size_t)kk * CIN * COUT;
        BF8 b0, b1;
#pragma unroll
        for (int j = 0; j < 8; ++j) {
          const int krow = lk * 8 + j;
          b0.u[j] = f2bf(wk[krow * COUT + lm]);
          b1.u[j] = f2bf(wk[krow * COUT + lm + 16]);
        }

        const int G = (n + 31) >> 5;

#define LOADE(dst0, dst1, g)                                                 \
  {                                                                          \
    const int _e0 = (g) * 32 + lm;                                           \
    dst0 = (_e0 < n) ? __builtin_nontemporal_load(entries + s + _e0) : 0u;   \
    dst1 = (_e0 + 16 < n)                                                    \
               ? __builtin_nontemporal_load(entries + s + _e0 + 16)          \
               : 0u;                                                         \
  }
#define LOADX(dsta, dstb, u0_, u1_)                                          \
  {                                                                          \
    dsta.v = *reinterpret_cast<const bf16x8*>(xbf + (size_t)(u0_ >> 8) * CIN \
                                              + lk * 8);                     \
    dstb.v = *reinterpret_cast<const bf16x8*>(xbf + (size_t)(u1_ >> 8) * CIN \
                                              + lk * 8);                     \
  }

        unsigned cu0, cu1, nu0 = 0, nu1 = 0;
        BF8 ca0, ca1;
        LOADE(cu0, cu1, 0);
        if (G > 1) LOADE(nu0, nu1, 1);
        LOADX(ca0, ca1, cu0, cu1);

        for (int g = 0; g < G; ++g) {
          unsigned fu0 = 0, fu1 = 0;
          if (g + 2 < G) LOADE(fu0, fu1, g + 2);

          const int base = g * 32;
          const bool v0 = (base + lm) < n;
          const bool v1 = (base + lm + 16) < n;
          const int ol0 = v0 ? (int)(cu0 & 255u) : 256;
          const int ol1 = v1 ? (int)(cu1 & 255u) : 256;

          f32x4 c00 = {0.f, 0.f, 0.f, 0.f}, c01 = {0.f, 0.f, 0.f, 0.f};
          f32x4 c10 = {0.f, 0.f, 0.f, 0.f}, c11 = {0.f, 0.f, 0.f, 0.f};
          c00 = __builtin_amdgcn_mfma_f32_16x16x32_bf16(ca0.v, b0.v, c00, 0, 0, 0);
          c01 = __builtin_amdgcn_mfma_f32_16x16x32_bf16(ca0.v, b1.v, c01, 0, 0, 0);
          c10 = __builtin_amdgcn_mfma_f32_16x16x32_bf16(ca1.v, b0.v, c10, 0, 0, 0);
          c11 = __builtin_amdgcn_mfma_f32_16x16x32_bf16(ca1.v, b1.v, c11, 0, 0, 0);

#pragma unroll
          for (int i = 0; i < 4; ++i) {
            const int r = lk * 4 + i;
            const int o0 = __shfl(ol0, r);
            const int o1 = __shfl(ol1, r);
            atomicAdd(&sacc[o0 * 33 + lm], c00[i]);
            atomicAdd(&sacc[o0 * 33 + lm + 16], c01[i]);
            atomicAdd(&sacc[o1 * 33 + lm], c10[i]);
            atomicAdd(&sacc[o1 * 33 + lm + 16], c11[i]);
          }

          if (g + 1 < G) {
            LOADX(ca0, ca1, nu0, nu1);
            cu0 = nu0; cu1 = nu1;
            nu0 = fu0; nu1 = fu1;
          }
        }
#undef LOADE
#undef LOADX
      }
      __syncthreads();

      // merge tile into out (NT so the 2GB out-stream doesn't evict the slice)
#pragma unroll
      for (int r = 0; r < 8; ++r) {
        const int idx = r * 256 + tid;  // float4 index within tile [0,2048)
        const int row = idx >> 3;
        const int f4c = idx & 7;
        const int grow = t * TR + row;
        if (grow < NOUT) {
          f32x4 v;
          v[0] = sacc[row * 33 + f4c * 4 + 0];
          v[1] = sacc[row * 33 + f4c * 4 + 1];
          v[2] = sacc[row * 33 + f4c * 4 + 2];
          v[3] = sacc[row * 33 + f4c * 4 + 3];
          f32x4* op = reinterpret_cast<f32x4*>(out) + (size_t)grow * 8 + f4c;
          const f32x4 base =
              (sl == 0) ? b4[f4c] : __builtin_nontemporal_load(op);
          v[0] += base[0]; v[1] += base[1]; v[2] += base[2]; v[3] += base[3];
          __builtin_nontemporal_store(v, op);
        }
      }
    }
  }
}

// ---------------- last-resort fallback (R1 path) ----------------
__global__ __launch_bounds__(256) void bias_init_kernel(
    float* __restrict__ out, const float* __restrict__ bias) {
  float4 b[8];
#pragma unroll
  for (int j = 0; j < 8; ++j) b[j] = reinterpret_cast<const float4*>(bias)[j];
  const size_t total4 = (size_t)NOUT * COUT / 4;
  const size_t stride = (size_t)gridDim.x * blockDim.x;
  for (size_t i = (size_t)blockIdx.x * blockDim.x + threadIdx.x; i < total4;
       i += stride)
    reinterpret_cast<float4*>(out)[i] = b[i & 7];
}

__global__ __launch_bounds__(256) void scatter_gemm_kernel(
    const float* __restrict__ x, const float* __restrict__ weights,
    const int* __restrict__ in_inds, const int* __restrict__ out_inds,
    float* __restrict__ out) {
  const int k = blockIdx.y;
  const int e = blockIdx.x * 256 + threadIdx.x;
  if (e >= RULES) return;
  const int ii = in_inds[(size_t)k * RULES + e];
  const int oi = out_inds[(size_t)k * RULES + e];
  float xr[CIN];
  const float4* xrow = reinterpret_cast<const float4*>(x + (size_t)ii * CIN);
#pragma unroll
  for (int j = 0; j < 8; ++j) {
    float4 v = xrow[j];
    xr[4 * j] = v.x; xr[4 * j + 1] = v.y; xr[4 * j + 2] = v.z; xr[4 * j + 3] = v.w;
  }
  const float* wk = weights + (size_t)k * CIN * COUT;
  float acc[COUT];
#pragma unroll
  for (int c = 0; c < COUT; ++c) acc[c] = 0.f;
#pragma unroll
  for (int i = 0; i < CIN; ++i) {
    const float xi = xr[i];
#pragma unroll
    for (int c = 0; c < COUT; ++c) acc[c] += xi * wk[i * COUT + c];
  }
#pragma unroll
  for (int c = 0; c < COUT; ++c) atomicAdd(&out[(size_t)oi * COUT + c], acc[c]);
}

static inline size_t align4k(size_t v) { return (v + 4095) & ~(size_t)4095; }

extern "C" void kernel_launch(void* const* d_in, const int* in_sizes, int n_in,
                              void* d_out, int out_size, void* d_ws,
                              size_t ws_size, hipStream_t stream) {
  const float* x        = (const float*)d_in[0];
  const float* weights  = (const float*)d_in[1];
  const float* bias     = (const float*)d_in[2];
  const int*   in_inds  = (const int*)d_in[3];
  const int*   out_inds = (const int*)d_in[4];
  float*       out      = (float*)d_out;
  char*        ws       = (char*)d_ws;

  dim3 rgrid((RULES + 255) / 256, K3);

  // workspace layout
  const size_t o_cnt = 0;
  const size_t o_ovfc = align4k(o_cnt + (size_t)NBINS2 * 4);
  const size_t o_ovf = o_ovfc + 4096;
  const size_t o_entries = align4k(o_ovf + (size_t)OVFCAP * 8);
  const size_t o_xbf = align4k(o_entries + (size_t)NBINS2 * CAPB2 * 4);
  const size_t REQ = o_xbf + (size_t)NIN * CIN * 2;

  if (ws_size >= REQ) {
    int* cnt = (int*)(ws + o_cnt);
    int* ovfc = (int*)(ws + o_ovfc);
    unsigned* ovf = (unsigned*)(ws + o_ovf);
    unsigned* entries = (unsigned*)(ws + o_entries);
    unsigned short* xbf = (unsigned short*)(ws + o_xbf);

    hipMemsetAsync(ws, 0, o_ovfc + 4, stream);  // cnt + ovfc
    place_cap_kernel<<<rgrid, 256, 0, stream>>>(in_inds, out_inds, cnt,
                                                entries, ovfc, ovf);
    xcvt_kernel<<<2048, 256, 0, stream>>>(x, xbf);
    gather_sliced_kernel<<<NBLK, 256, 0, stream>>>(xbf, weights, bias, cnt,
                                                   entries, out);
    fixup_kernel<<<16, 256, 0, stream>>>(x, weights, ovfc, ovf, out);
  } else {
    bias_init_kernel<<<2048, 256, 0, stream>>>(out, bias);
    scatter_gemm_kernel<<<rgrid, 256, 0, stream>>>(x, weights, in_inds,
                                                   out_inds, out);
  }
}

// Round 9
// 8647.861 us; speedup vs baseline: 1.0395x; 1.0395x over previous
//
#include <hip/hip_runtime.h>

// SparseConv3d rulebook scatter-GEMM, MI355X (gfx950)
// R9: bins = (k, 256-row out-tile, input-half). Slice-phased gather via TWO
// kernel launches (kernel boundary = device-wide phase fence; no coop API).
// Within a launch every block gathers from the same 64 MB bf16 x-slice ->
// L3-resident -> beats the ~405 GB/s random-64B DRAM ceiling (R3-R7).
// Slice 0: out = acc + bias. Slice 1: out += acc (NT merge). Fixup last.

#define K3    27
#define RULES 1000000
#define CIN   32
#define COUT  32
#define NIN   2000000
#define NOUT  2000000
#define TR    256
#define NT    ((NOUT + TR - 1) / TR)   // 7813 tiles
#define NSLICE 2
#define SLICE_SHIFT 20                 // 1M input rows/slice = 64 MB bf16
#define NBINS2 (K3 * NT * NSLICE)      // 421,902 bins
#define CAPB2 120                      // avg 64 rules/bin (+7 sigma)
#define OVFCAP 4096

typedef float f32x4 __attribute__((ext_vector_type(4)));
typedef short bf16x8 __attribute__((ext_vector_type(8)));
typedef unsigned short us8 __attribute__((ext_vector_type(8)));

union BF8 {
  bf16x8 v;
  unsigned short u[8];
};

static __device__ inline unsigned short f2bf(float f) {
  unsigned u = __builtin_bit_cast(unsigned, f);
  u += 0x7fffu + ((u >> 16) & 1u);   // RNE
  return (unsigned short)(u >> 16);
}

// ---------------- x -> bf16 conversion ----------------
__global__ __launch_bounds__(256) void xcvt_kernel(
    const float* __restrict__ x, unsigned short* __restrict__ xbf) {
  const size_t n8 = (size_t)NIN * CIN / 8;
  const size_t stride = (size_t)gridDim.x * 256;
  for (size_t i = (size_t)blockIdx.x * 256 + threadIdx.x; i < n8; i += stride) {
    const f32x4* p = reinterpret_cast<const f32x4*>(x + i * 8);
    const f32x4 a = __builtin_nontemporal_load(p);
    const f32x4 b = __builtin_nontemporal_load(p + 1);
    us8 o;
    o[0] = f2bf(a[0]); o[1] = f2bf(a[1]); o[2] = f2bf(a[2]); o[3] = f2bf(a[3]);
    o[4] = f2bf(b[0]); o[5] = f2bf(b[1]); o[6] = f2bf(b[2]); o[7] = f2bf(b[3]);
    __builtin_nontemporal_store(o, reinterpret_cast<us8*>(xbf + i * 8));
  }
}

// ---------------- capacity-binned single-pass place ----------------
__global__ __launch_bounds__(256) void place_cap_kernel(
    const int* __restrict__ in_inds, const int* __restrict__ out_inds,
    int* __restrict__ cnt, unsigned* __restrict__ entries,
    int* __restrict__ ovfc, unsigned* __restrict__ ovf) {
  const int k = blockIdx.y;
  const int e = blockIdx.x * 256 + threadIdx.x;
  if (e >= RULES) return;
  const size_t idx = (size_t)k * RULES + e;
  const int oi = __builtin_nontemporal_load(out_inds + idx);
  const int ii = __builtin_nontemporal_load(in_inds + idx);
  const int bin = (k * NT + (oi >> 8)) * NSLICE + (ii >> SLICE_SHIFT);
  const int pos = atomicAdd(&cnt[bin], 1);
  if (pos < CAPB2) {
    __builtin_nontemporal_store(((unsigned)ii << 8) | (unsigned)(oi & 255),
                                entries + (size_t)bin * CAPB2 + pos);
  } else {
    const int op = atomicAdd(ovfc, 1);
    if (op < OVFCAP) {
      ovf[op * 2] = (unsigned)ii;
      ovf[op * 2 + 1] = (unsigned)oi | ((unsigned)k << 21);
    }
  }
}

// ---------------- fixup for (expected-zero) bin overflow ----------------
__global__ __launch_bounds__(256) void fixup_kernel(
    const float* __restrict__ x, const float* __restrict__ weights,
    const int* __restrict__ ovfc, const unsigned* __restrict__ ovf,
    float* __restrict__ out) {
  const int m = min(*ovfc, OVFCAP);
  const int total = m * 32;
  for (int idx = blockIdx.x * 256 + threadIdx.x; idx < total;
       idx += gridDim.x * 256) {
    const int rr = idx >> 5, c = idx & 31;
    const unsigned ii = ovf[rr * 2];
    const unsigned w1 = ovf[rr * 2 + 1];
    const unsigned oi = w1 & 0x1FFFFFu;
    const int k = (int)(w1 >> 21);
    const float* xr = x + (size_t)ii * CIN;
    const float* wk = weights + (size_t)k * CIN * COUT;
    float acc = 0.f;
#pragma unroll
    for (int i = 0; i < CIN; ++i) acc += xr[i] * wk[i * COUT + c];
    atomicAdd(&out[(size_t)oi * COUT + c], acc);
  }
}

// ---------------- slice-phased MFMA gather (one launch per slice) --------
// Block = one 256-row out tile, 4 waves. Wave w covers k = w, w+4, ...
// Per bin: 3 batched masked 32-rule MFMA units (lambda=64), loads issued
// before any use. C layout (m89): col=lane&15, row=(lane>>4)*4+i. Scatter
// via shfl + LDS atomicAdd into [257][33] (row 256 = dump). Epilogue:
// SL==0 -> out = acc + bias (NT store); SL==1 -> out += acc (NT ld/st).
template <int SL>
__global__ __launch_bounds__(256, 4) void gather_slice_kernel(
    const unsigned short* __restrict__ xbf, const float* __restrict__ weights,
    const float* __restrict__ bias, const int* __restrict__ cnt,
    const unsigned* __restrict__ entries, float* __restrict__ out) {
  __shared__ float sacc[257 * 33];
  const int t = blockIdx.x;
  const int tid = threadIdx.x;
  const int wave = tid >> 6;
  const int lane = tid & 63;
  const int lm = lane & 15;   // rule-in-unit / cout col
  const int lk = lane >> 4;   // K-chunk selector

  for (int i = tid; i < 257 * 33; i += 256) sacc[i] = 0.f;
  __syncthreads();

#define LOADE(d0, d1, g)                                                     \
  {                                                                          \
    const int _e = (g) * 32 + lm;                                            \
    d0 = (_e < n) ? __builtin_nontemporal_load(entries + s + _e) : 0u;       \
    d1 = (_e + 16 < n) ? __builtin_nontemporal_load(entries + s + _e + 16)   \
                       : 0u;                                                 \
  }
#define LOADX(da, db, u0, u1)                                                \
  {                                                                          \
    da.v = *reinterpret_cast<const bf16x8*>(xbf + (size_t)((u0) >> 8) * CIN  \
                                            + lk * 8);                       \
    db.v = *reinterpret_cast<const bf16x8*>(xbf + (size_t)((u1) >> 8) * CIN  \
                                            + lk * 8);                       \
  }
#define PROC(g, ua, ub, xa, xb)                                              \
  {                                                                          \
    const bool _v0 = ((g) * 32 + lm) < n;                                    \
    const bool _v1 = ((g) * 32 + 16 + lm) < n;                               \
    const int _ol0 = _v0 ? (int)((ua) & 255u) : 256;                         \
    const int _ol1 = _v1 ? (int)((ub) & 255u) : 256;                         \
    f32x4 c00 = {0.f, 0.f, 0.f, 0.f}, c01 = {0.f, 0.f, 0.f, 0.f};            \
    f32x4 c10 = {0.f, 0.f, 0.f, 0.f}, c11 = {0.f, 0.f, 0.f, 0.f};            \
    c00 = __builtin_amdgcn_mfma_f32_16x16x32_bf16(xa.v, b0.v, c00, 0, 0, 0); \
    c01 = __builtin_amdgcn_mfma_f32_16x16x32_bf16(xa.v, b1.v, c01, 0, 0, 0); \
    c10 = __builtin_amdgcn_mfma_f32_16x16x32_bf16(xb.v, b0.v, c10, 0, 0, 0); \
    c11 = __builtin_amdgcn_mfma_f32_16x16x32_bf16(xb.v, b1.v, c11, 0, 0, 0); \
    _Pragma("unroll") for (int _i = 0; _i < 4; ++_i) {                       \
      const int _r = lk * 4 + _i;                                            \
      const int _o0 = __shfl(_ol0, _r);                                      \
      const int _o1 = __shfl(_ol1, _r);                                      \
      atomicAdd(&sacc[_o0 * 33 + lm], c00[_i]);                              \
      atomicAdd(&sacc[_o0 * 33 + lm + 16], c01[_i]);                         \
      atomicAdd(&sacc[_o1 * 33 + lm], c10[_i]);                              \
      atomicAdd(&sacc[_o1 * 33 + lm + 16], c11[_i]);                         \
    }                                                                        \
  }

#pragma unroll
  for (int kidx = 0; kidx < 7; ++kidx) {
    const int kk = wave + kidx * 4;
    if (kk >= K3) continue;
    const int bin = (kk * NT + t) * NSLICE + SL;
    int n = __builtin_amdgcn_readfirstlane(cnt[bin]);
    n = min(n, CAPB2);
    if (n == 0) continue;
    const size_t s = (size_t)bin * CAPB2;

    // B fragments for W[kk] (tiny, cache-hot)
    const float* __restrict__ wk = weights + (size_t)kk * CIN * COUT;
    BF8 b0, b1;
#pragma unroll
    for (int j = 0; j < 8; ++j) {
      const int krow = lk * 8 + j;
      b0.u[j] = f2bf(wk[krow * COUT + lm]);
      b1.u[j] = f2bf(wk[krow * COUT + lm + 16]);
    }

    // 3 units batched: all loads issued before any use (MLP)
    unsigned e0a, e0b, e1a, e1b, e2a, e2b;
    LOADE(e0a, e0b, 0);
    LOADE(e1a, e1b, 1);
    LOADE(e2a, e2b, 2);
    BF8 xa0, xb0, xa1, xb1, xa2, xb2;
    LOADX(xa0, xb0, e0a, e0b);
    LOADX(xa1, xb1, e1a, e1b);
    LOADX(xa2, xb2, e2a, e2b);
    PROC(0, e0a, e0b, xa0, xb0);
    PROC(1, e1a, e1b, xa1, xb1);
    PROC(2, e2a, e2b, xa2, xb2);
    // rare tail (P(n>96) small)
    const int G = (n + 31) >> 5;
    for (int g = 3; g < G; ++g) {
      unsigned ua, ub;
      LOADE(ua, ub, g);
      BF8 xga, xgb;
      LOADX(xga, xgb, ua, ub);
      PROC(g, ua, ub, xga, xgb);
    }
  }
#undef LOADE
#undef LOADX
#undef PROC
  __syncthreads();

  const f32x4* __restrict__ b4 = reinterpret_cast<const f32x4*>(bias);
#pragma unroll
  for (int rr = 0; rr < 8; ++rr) {
    const int idx = rr * 256 + tid;  // float4 index within tile
    const int row = idx >> 3;
    const int f4c = idx & 7;
    const int grow = t * TR + row;
    if (grow < NOUT) {
      f32x4 v;
      v[0] = sacc[row * 33 + f4c * 4 + 0];
      v[1] = sacc[row * 33 + f4c * 4 + 1];
      v[2] = sacc[row * 33 + f4c * 4 + 2];
      v[3] = sacc[row * 33 + f4c * 4 + 3];
      f32x4* op = reinterpret_cast<f32x4*>(out) + (size_t)grow * 8 + f4c;
      const f32x4 base = (SL == 0) ? b4[f4c] : __builtin_nontemporal_load(op);
      v[0] += base[0]; v[1] += base[1]; v[2] += base[2]; v[3] += base[3];
      __builtin_nontemporal_store(v, op);
    }
  }
}

// ---------------- fallback (R1 path) ----------------
__global__ __launch_bounds__(256) void bias_init_kernel(
    float* __restrict__ out, const float* __restrict__ bias) {
  float4 b[8];
#pragma unroll
  for (int j = 0; j < 8; ++j) b[j] = reinterpret_cast<const float4*>(bias)[j];
  const size_t total4 = (size_t)NOUT * COUT / 4;
  const size_t stride = (size_t)gridDim.x * blockDim.x;
  for (size_t i = (size_t)blockIdx.x * blockDim.x + threadIdx.x; i < total4;
       i += stride)
    reinterpret_cast<float4*>(out)[i] = b[i & 7];
}

__global__ __launch_bounds__(256) void scatter_gemm_kernel(
    const float* __restrict__ x, const float* __restrict__ weights,
    const int* __restrict__ in_inds, const int* __restrict__ out_inds,
    float* __restrict__ out) {
  const int k = blockIdx.y;
  const int e = blockIdx.x * 256 + threadIdx.x;
  if (e >= RULES) return;
  const int ii = in_inds[(size_t)k * RULES + e];
  const int oi = out_inds[(size_t)k * RULES + e];
  float xr[CIN];
  const float4* xrow = reinterpret_cast<const float4*>(x + (size_t)ii * CIN);
#pragma unroll
  for (int j = 0; j < 8; ++j) {
    float4 v = xrow[j];
    xr[4 * j] = v.x; xr[4 * j + 1] = v.y; xr[4 * j + 2] = v.z; xr[4 * j + 3] = v.w;
  }
  const float* wk = weights + (size_t)k * CIN * COUT;
  float acc[COUT];
#pragma unroll
  for (int c = 0; c < COUT; ++c) acc[c] = 0.f;
#pragma unroll
  for (int i = 0; i < CIN; ++i) {
    const float xi = xr[i];
#pragma unroll
    for (int c = 0; c < COUT; ++c) acc[c] += xi * wk[i * COUT + c];
  }
#pragma unroll
  for (int c = 0; c < COUT; ++c) atomicAdd(&out[(size_t)oi * COUT + c], acc[c]);
}

static inline size_t align4k(size_t v) { return (v + 4095) & ~(size_t)4095; }

extern "C" void kernel_launch(void* const* d_in, const int* in_sizes, int n_in,
                              void* d_out, int out_size, void* d_ws,
                              size_t ws_size, hipStream_t stream) {
  const float* x        = (const float*)d_in[0];
  const float* weights  = (const float*)d_in[1];
  const float* bias     = (const float*)d_in[2];
  const int*   in_inds  = (const int*)d_in[3];
  const int*   out_inds = (const int*)d_in[4];
  float*       out      = (float*)d_out;
  char*        ws       = (char*)d_ws;

  dim3 rgrid((RULES + 255) / 256, K3);

  // workspace layout
  const size_t o_cnt = 0;
  const size_t o_ovfc = align4k(o_cnt + (size_t)NBINS2 * 4);
  const size_t o_ovf = o_ovfc + 4096;
  const size_t o_entries = align4k(o_ovf + (size_t)OVFCAP * 8);
  const size_t o_xbf = align4k(o_entries + (size_t)NBINS2 * CAPB2 * 4);
  const size_t REQ = o_xbf + (size_t)NIN * CIN * 2;   // ~332 MB

  if (ws_size >= REQ) {
    int* cnt = (int*)(ws + o_cnt);
    int* ovfc = (int*)(ws + o_ovfc);
    unsigned* ovf = (unsigned*)(ws + o_ovf);
    unsigned* entries = (unsigned*)(ws + o_entries);
    unsigned short* xbf = (unsigned short*)(ws + o_xbf);

    hipMemsetAsync(ws, 0, o_ovfc + 4, stream);  // cnt + ovfc
    place_cap_kernel<<<rgrid, 256, 0, stream>>>(in_inds, out_inds, cnt,
                                                entries, ovfc, ovf);
    xcvt_kernel<<<2048, 256, 0, stream>>>(x, xbf);
    gather_slice_kernel<0><<<NT, 256, 0, stream>>>(xbf, weights, bias, cnt,
                                                   entries, out);
    gather_slice_kernel<1><<<NT, 256, 0, stream>>>(xbf, weights, bias, cnt,
                                                   entries, out);
    fixup_kernel<<<16, 256, 0, stream>>>(x, weights, ovfc, ovf, out);
  } else {
    bias_init_kernel<<<2048, 256, 0, stream>>>(out, bias);
    scatter_gemm_kernel<<<rgrid, 256, 0, stream>>>(x, weights, in_inds,
                                                   out_inds, out);
  }
}